// Round 5
// baseline (269.642 us; speedup 1.0000x reference)
//
#include <hip/hip_runtime.h>

#define BCNT 16
#define TT 1024
#define DIN 384
#define H1 1024
#define H2 1024
#define KW 9

typedef __attribute__((ext_vector_type(8))) short bhalf8;   // 8 bf16 in 4 VGPRs
typedef __attribute__((ext_vector_type(4))) float f32x4;

typedef const __attribute__((address_space(1))) void* gas_ptr;
typedef __attribute__((address_space(3))) void* lds_ptr;

__device__ __forceinline__ float bf2f(unsigned short u) {
    return __uint_as_float(((unsigned int)u) << 16);
}
__device__ __forceinline__ unsigned short f2bf(float f) {
    unsigned int u = __float_as_uint(f);
    unsigned int r = (u + 0x7FFFu + ((u >> 16) & 1u)) >> 16;  // RNE
    return (unsigned short)r;
}
// mish(x) = x*tanh(log1p(e^x)) = x*(u^2+2u)/(u^2+2u+2), u=e^x (exact algebra)
__device__ __forceinline__ float mish_f(float x) {
    if (x > 20.f) return x;
    float u = __expf(x);
    float n = u * u + 2.f * u;
    return x * n / (n + 2.f);
}

// ---------------- prep kernels ----------------

// fused f32->bf16 cvt for input, w1_w, w2_w + zero sumsq (one launch)
__global__ __launch_bounds__(256) void k_cvt3z(
    const float* __restrict__ s0, unsigned short* __restrict__ d0, int n0,
    const float* __restrict__ s1, unsigned short* __restrict__ d1, int n1,
    const float* __restrict__ s2, unsigned short* __restrict__ d2, int n2,
    float* __restrict__ zb, int n3) {
    int i = blockIdx.x * 256 + threadIdx.x;
    const float* s; unsigned short* d; int j = i;
    if (i < n0) { s = s0; d = d0; }
    else if ((j = i - n0) < n1) { s = s1; d = d1; }
    else if ((j = i - n0 - n1) < n2) { s = s2; d = d2; }
    else if ((j = i - n0 - n1 - n2) < n3) {
        ((float4*)zb)[j] = make_float4(0.f, 0.f, 0.f, 0.f);
        return;
    } else return;
    float4 v = ((const float4*)s)[j];
    ushort4 o;
    o.x = f2bf(v.x); o.y = f2bf(v.y); o.z = f2bf(v.z); o.w = f2bf(v.w);
    ((ushort4*)d)[j] = o;
}

// per-(b,k): norm of d_w over c, then write dwn_s[b,c,k] = d_w/n * d_g * T
__global__ void k_norm_dwn(const float* __restrict__ d_w, const float* __restrict__ d_g,
                           float* __restrict__ dwn_s) {
    int idx = blockIdx.x;           // b*KW + k
    int b = idx / KW, k = idx % KW;
    float s = 0.f;
    for (int c = threadIdx.x; c < H1; c += 256) {
        float v = d_w[((size_t)b * H1 + c) * KW + k];
        s += v * v;
    }
    __shared__ float red[256];
    __shared__ float nsh;
    red[threadIdx.x] = s; __syncthreads();
    for (int st = 128; st > 0; st >>= 1) {
        if (threadIdx.x < st) red[threadIdx.x] += red[threadIdx.x + st];
        __syncthreads();
    }
    if (threadIdx.x == 0) nsh = fmaxf(sqrtf(red[0]), 1e-12f);
    __syncthreads();
    float n = nsh;
    for (int c = threadIdx.x; c < H1; c += 256) {
        size_t o = ((size_t)b * H1 + c) * KW + k;
        dwn_s[o] = d_w[o] / n * d_g[b * H1 + c] * (float)TT;
    }
}

// transpose+scale p_w AND per-(b,o) sumsq. Vectorized: 32c x 128o tile,
// float4 (16B/lane) reads, 2x bhalf8 (32B/thread) transposed writes.
__global__ __launch_bounds__(256) void k_tpw3(const float* __restrict__ p_w,
                                              const float* __restrict__ p_g,
                                              unsigned short* __restrict__ pwTu,
                                              float* __restrict__ sumsq) {
    __shared__ float tile[32][132];
    __shared__ float sred[8][32][4];
    __shared__ float pg[32];
    const int tid = threadIdx.x;
    const int tx = tid & 31, ty = tid >> 5;         // 32 x 8
    const int c0 = blockIdx.x * 32, o0 = blockIdx.y * 128, b = blockIdx.z;
    if (tid < 32) pg[tid] = p_g[(size_t)b * H1 + c0 + tid];
    const float4* pw4 = (const float4*)p_w;
    float s0 = 0.f, s1 = 0.f, s2 = 0.f, s3 = 0.f;
#pragma unroll
    for (int j = 0; j < 4; j++) {
        int cl = ty + j * 8;
        float4 v = pw4[(size_t)(b * H1 + c0 + cl) * (H2 / 4) + (o0 / 4) + tx];
        *(float4*)&tile[cl][tx * 4] = v;
        s0 += v.x * v.x; s1 += v.y * v.y; s2 += v.z * v.z; s3 += v.w * v.w;
    }
    sred[ty][tx][0] = s0; sred[ty][tx][1] = s1;
    sred[ty][tx][2] = s2; sred[ty][tx][3] = s3;
    __syncthreads();
    if (tid < 128) {
        int txo = tid >> 2, q = tid & 3;
        float t = 0.f;
#pragma unroll
        for (int r = 0; r < 8; r++) t += sred[r][txo][q];
        atomicAdd(&sumsq[(size_t)b * H2 + o0 + txo * 4 + q], t);
    }
    const int ol = tid >> 1, half = (tid & 1) * 16;
    unsigned short outv[16];
#pragma unroll
    for (int i = 0; i < 16; i++)
        outv[i] = f2bf(tile[half + i][ol] * pg[half + i]);
    unsigned short* dst = &pwTu[((size_t)b * H2 + o0 + ol) * H1 + c0 + half];
    *(bhalf8*)dst = *(const bhalf8*)&outv[0];
    *(bhalf8*)&dst[8] = *(const bhalf8*)&outv[8];
}

// depthwise conv along T. Vectorized: 4 channels/thread (ushort4, 8B/lane),
// t-block 16 -> grid (64,1,16) = 1024 blocks = 4 blk/CU (16 waves/CU TLP).
__global__ __launch_bounds__(256) void k_conv4(const unsigned short* __restrict__ h,
                                               const float* __restrict__ dwn_s,
                                               const float* __restrict__ d_b,
                                               unsigned short* __restrict__ y) {
    const int tid = threadIdx.x;
    const int c = tid * 4;
    const int t0 = blockIdx.x * 16;
    const int b = blockIdx.z;
    const ushort4* hb = (const ushort4*)(h + (size_t)b * TT * H1);
    ushort4* yb = (ushort4*)(y + (size_t)b * TT * H1);
    float kk[KW][4], db[4];
#pragma unroll
    for (int q = 0; q < 4; q++) {
        db[q] = d_b[b * H1 + c + q];
#pragma unroll
        for (int i = 0; i < KW; i++)
            kk[i][q] = dwn_s[((size_t)b * H1 + c + q) * KW + i];
    }
    float w[KW][4];
#pragma unroll
    for (int i = 0; i < 8; i++) {
        int t = t0 - 4 + i;
        if (t >= 0) {
            ushort4 v = hb[(size_t)t * (H1 / 4) + tid];
            w[i][0] = bf2f(v.x); w[i][1] = bf2f(v.y);
            w[i][2] = bf2f(v.z); w[i][3] = bf2f(v.w);
        } else { w[i][0] = w[i][1] = w[i][2] = w[i][3] = 0.f; }
    }
#pragma unroll
    for (int j = 0; j < 16; j++) {
        const int t = t0 + j, tl = t + 4;
        if (tl < TT) {
            ushort4 v = hb[(size_t)tl * (H1 / 4) + tid];
            w[8][0] = bf2f(v.x); w[8][1] = bf2f(v.y);
            w[8][2] = bf2f(v.z); w[8][3] = bf2f(v.w);
        } else { w[8][0] = w[8][1] = w[8][2] = w[8][3] = 0.f; }
        float a0 = db[0], a1 = db[1], a2 = db[2], a3 = db[3];
#pragma unroll
        for (int i = 0; i < KW; i++) {
            a0 += kk[i][0] * w[i][0]; a1 += kk[i][1] * w[i][1];
            a2 += kk[i][2] * w[i][2]; a3 += kk[i][3] * w[i][3];
        }
        ushort4 o;
        o.x = f2bf(a0); o.y = f2bf(a1); o.z = f2bf(a2); o.w = f2bf(a3);
        yb[(size_t)t * (H1 / 4) + tid] = o;
#pragma unroll
        for (int i = 0; i < 8; i++) {
            w[i][0] = w[i + 1][0]; w[i][1] = w[i + 1][1];
            w[i][2] = w[i + 1][2]; w[i][3] = w[i + 1][3];
        }
    }
}

// ------- gemm_dp: 256x256 tile, BK=32, ring-3 LDS, fine-phase interleave -------
// C[m,n] = sum_k A[m,k]*B[n,k], bf16 K-contiguous. 512 thr = 8 waves (2M x 4N),
// wave out 128x64, acc[8][4]. LDS: 3 slots x (A 16KB + B 16KB) = 96KB -> 1 blk/CU.
// M-row PAIRS packed into 64-elem (128B) LDS rows, XOR swizzle g^(R&7) -- the
// exact round-0 geometry that measured 0 bank conflicts.
// Pipeline: stage tile kt+2 (slot (kt+2)%3, distinct from kt%3 and (kt+1)%3)
// while computing kt. Per K-step 2 phases:
//  P1: 8 ds_read (bf0-3, af0-3) | stage 2 A-loads | bar | lgkm(0) | 16 MFMA | bar
//  P2: 4 ds_read (af4-7)        | stage 2 B-loads | bar | lgkm(0) | 16 MFMA |
//      vmcnt(4) | bar
// Safety (provable): vmcnt(4) allows only THIS step's 4 stage-loads pending ->
// tile kt+1 landed before its reads. Slot (kt+2)%3's last readers (step kt-1)
// drained via their lgkm(0) before kt-1's closing barrier. sched_barrier(0)
// after each lgkm stops MFMA hoisting (rule #18).
// MODE 0: C=bf16(mish(v+bias[n]));  MODE 1: C=bf16(v*rsqrt(sumsq)+bias) batched.
template <int MODE, int GS>
__global__ __launch_bounds__(512, 2) void gemm_dp(
    const unsigned short* __restrict__ A, const unsigned short* __restrict__ Bm,
    unsigned short* __restrict__ Cp, int Kdim, int lda, int ldb, int ldc,
    long sA, long sB, long sC,
    const float* __restrict__ bias, int biasStride,
    const float* __restrict__ sumsq) {
    __shared__ __attribute__((aligned(16))) unsigned short As[3][128 * 64];
    __shared__ __attribute__((aligned(16))) unsigned short Bs[3][128 * 64];

    const int tid = threadIdx.x;
    const int lane = tid & 63, wv = tid >> 6;       // 8 waves
    const int wr = wv >> 2, wc = wv & 3;            // 2 x 4 wave grid

    int bx, by, bz;
    {
        int l = blockIdx.x;                         // 256 blocks, 1/CU
        int xcd = l & 7, s = l >> 3;                // s: 0..31
        if constexpr (GS == 0) { bz = 0; bx = xcd * 8 + (s & 7); by = s >> 3; }
        else { bz = xcd * 2 + (s >> 4); int u = s & 15; bx = u & 3; by = u >> 2; }
    }
    const int bm = bx * 256, bn = by * 256;
    const unsigned short* Ab = A + (size_t)sA * bz;
    const unsigned short* Bb = Bm + (size_t)sB * bz;

    // staging: chunk = 8 LDS-rows (16 M-rows x 32 K). LDS dest linear
    // (base + lane*16B); source granule XOR-swizzled: gl = (lane&7)^(rS&7).
    // LDS slot (R, p) holds global granule p^(R&7); granule g: m-par = g>>2,
    // k-octet = g&3.
    const int rSl = lane >> 3;                      // LDS-row within chunk
    const int gSl = (lane & 7) ^ (rSl & 7);         // source granule
    const int mOf = 2 * rSl + (gSl >> 2);           // m-row offset within 16
    const int kOf = (gSl & 3) * 8;                  // k offset within 32

    // frag-read offsets: row r -> LDS-row R=r>>1; granule gl=(r&1)*4+quad;
    // slot gsw = gl ^ (R&7); R&7 == (l16>>1)&7 for all frags (wr*64,wc*32,mi*8,ni*8 ≡ 0 mod 8)
    const int l16 = lane & 15, quad = lane >> 4;
    const int Rb = l16 >> 1;
    const int gsw = ((l16 & 1) * 4 + quad) ^ (Rb & 7);
    const int aoff = (wr * 64 + Rb) * 64 + gsw * 8;   // + mi*512
    const int boff = (wc * 32 + Rb) * 64 + gsw * 8;   // + ni*512

    f32x4 acc[8][4];
#pragma unroll
    for (int i = 0; i < 8; i++)
#pragma unroll
        for (int j = 0; j < 4; j++)
#pragma unroll
            for (int r = 0; r < 4; r++) acc[i][j][r] = 0.f;

    auto STAGE_A = [&](int kt) {
        const int slot = kt % 3;
        const int kofs = kt * 32 + kOf;
#pragma unroll
        for (int i = 0; i < 2; i++) {
            const int ch = wv + i * 8;               // 16 A-chunks
            const unsigned short* ga = Ab + (size_t)(bm + ch * 16 + mOf) * lda + kofs;
            __builtin_amdgcn_global_load_lds((gas_ptr)ga, (lds_ptr)&As[slot][ch * 512], 16, 0, 0);
        }
    };
    auto STAGE_B = [&](int kt) {
        const int slot = kt % 3;
        const int kofs = kt * 32 + kOf;
#pragma unroll
        for (int i = 0; i < 2; i++) {
            const int ch = wv + i * 8;               // 16 B-chunks
            const unsigned short* gb = Bb + (size_t)(bn + ch * 16 + mOf) * ldb + kofs;
            __builtin_amdgcn_global_load_lds((gas_ptr)gb, (lds_ptr)&Bs[slot][ch * 512], 16, 0, 0);
        }
    };

    const int nkt = Kdim / 32;
    STAGE_A(0); STAGE_B(0);                          // prologue: tiles 0,1
    STAGE_A(1); STAGE_B(1);
    asm volatile("s_waitcnt vmcnt(4)" ::: "memory"); // tile 0 landed
    __builtin_amdgcn_s_barrier();

    for (int kt = 0; kt < nkt; ++kt) {
        const unsigned short* Asl = &As[kt % 3][0];
        const unsigned short* Bsl = &Bs[kt % 3][0];
        const bool pf = (kt + 2 < nkt);

        // ---- P1: bf0-3 + af0-3, stage A(kt+2), 16 MFMA (mi 0-3) ----
        bhalf8 bfv[4], afv[4];
        bfv[0] = *(const bhalf8*)&Bsl[boff];
        bfv[1] = *(const bhalf8*)&Bsl[boff + 512];
        bfv[2] = *(const bhalf8*)&Bsl[boff + 1024];
        bfv[3] = *(const bhalf8*)&Bsl[boff + 1536];
        afv[0] = *(const bhalf8*)&Asl[aoff];
        afv[1] = *(const bhalf8*)&Asl[aoff + 512];
        afv[2] = *(const bhalf8*)&Asl[aoff + 1024];
        afv[3] = *(const bhalf8*)&Asl[aoff + 1536];
        if (pf) STAGE_A(kt + 2);
        __builtin_amdgcn_sched_barrier(0);
        __builtin_amdgcn_s_barrier();
        asm volatile("s_waitcnt lgkmcnt(0)" ::: "memory");
        __builtin_amdgcn_sched_barrier(0);
        __builtin_amdgcn_s_setprio(1);
#pragma unroll
        for (int mi = 0; mi < 4; mi++)
#pragma unroll
            for (int ni = 0; ni < 4; ni++)
                acc[mi][ni] = __builtin_amdgcn_mfma_f32_16x16x32_bf16(
                    afv[mi], bfv[ni], acc[mi][ni], 0, 0, 0);
        __builtin_amdgcn_s_setprio(0);
        __builtin_amdgcn_s_barrier();

        // ---- P2: af4-7, stage B(kt+2), 16 MFMA (mi 4-7), vmcnt, bar ----
        bhalf8 afw[4];
        afw[0] = *(const bhalf8*)&Asl[aoff + 4 * 512];
        afw[1] = *(const bhalf8*)&Asl[aoff + 5 * 512];
        afw[2] = *(const bhalf8*)&Asl[aoff + 6 * 512];
        afw[3] = *(const bhalf8*)&Asl[aoff + 7 * 512];
        if (pf) STAGE_B(kt + 2);
        __builtin_amdgcn_sched_barrier(0);
        __builtin_amdgcn_s_barrier();
        asm volatile("s_waitcnt lgkmcnt(0)" ::: "memory");
        __builtin_amdgcn_sched_barrier(0);
        __builtin_amdgcn_s_setprio(1);
#pragma unroll
        for (int mi = 0; mi < 4; mi++)
#pragma unroll
            for (int ni = 0; ni < 4; ni++)
                acc[4 + mi][ni] = __builtin_amdgcn_mfma_f32_16x16x32_bf16(
                    afw[mi], bfv[ni], acc[4 + mi][ni], 0, 0, 0);
        __builtin_amdgcn_s_setprio(0);
        if (pf) asm volatile("s_waitcnt vmcnt(4)" ::: "memory");
        else    asm volatile("s_waitcnt vmcnt(0)" ::: "memory");
        __builtin_amdgcn_s_barrier();
    }

    // epilogue: frag D row = quad*4+r, col = l16
#pragma unroll
    for (int mi = 0; mi < 8; mi++)
#pragma unroll
        for (int ni = 0; ni < 4; ni++)
#pragma unroll
            for (int r = 0; r < 4; r++) {
                int gm = bm + wr * 128 + mi * 16 + quad * 4 + r;
                int gn = bn + wc * 64 + ni * 16 + l16;
                float v = acc[mi][ni][r];
                size_t cidx = (size_t)sC * bz + (size_t)gm * ldc + gn;
                if constexpr (MODE == 0) {
                    v = mish_f(v + bias[gn]);
                    Cp[cidx] = f2bf(v);
                } else {
                    size_t si = (size_t)bz * biasStride + gn;
                    float rr = rsqrtf(fmaxf(sumsq[si], 1e-24f));
                    v = v * rr + bias[si];
                    Cp[cidx] = f2bf(v);
                }
            }
}

// ------- bf16 NT MFMA GEMM (round-0 structure): 128 x TN tile, BK=64 -------
// Used for G3 (N=384). MODE 2: C=f32 (v + bias[n] + bf2f(residbf[idx]))
template <int MODE, int SWIZ, int TN>
__global__ __launch_bounds__(256, 4) void gemm_nt(
    const unsigned short* __restrict__ A, const unsigned short* __restrict__ Bm,
    void* __restrict__ Cp, int Kdim, int lda, int ldb, int ldc,
    long sA, long sB, long sC,
    const float* __restrict__ bias, int biasStride,
    const float* __restrict__ sumsq,
    const unsigned short* __restrict__ residbf) {
    constexpr int WN = TN / 32;
    __shared__ __attribute__((aligned(16))) unsigned short Al[128 * 64];
    __shared__ __attribute__((aligned(16))) unsigned short Bl[TN * 64];

    const int tid = threadIdx.x;
    const int lane = tid & 63, wv = tid >> 6;

    int bx, by, bz;
    if constexpr (SWIZ) {
        int l = blockIdx.x;
        int xcd = l & 7, s = l >> 3;
        bz = xcd * 2 + (s >> 6);
        int u = s & 63;
        bx = u & 7; by = u >> 3;
    } else {
        bx = blockIdx.x; by = blockIdx.y; bz = blockIdx.z;
    }
    const int bm = bx * 128, bn = by * TN;

    const unsigned short* Ab = A + (size_t)sA * bz;
    const unsigned short* Bb = Bm + (size_t)sB * bz;

    const int rS = lane >> 3;
    const int cS = ((lane & 7) ^ (rS & 7)) * 8;

    const int wm = (wv >> 1) * 64, wn = (wv & 1) * (TN / 2);
    const int l16 = lane & 15, quad = lane >> 4;
    const int fx = l16 & 7;

    f32x4 acc[4][WN];
#pragma unroll
    for (int i = 0; i < 4; i++)
#pragma unroll
        for (int j = 0; j < WN; j++)
#pragma unroll
            for (int r = 0; r < 4; r++) acc[i][j][r] = 0.f;

    const int ktiles = Kdim / 64;
    for (int kt = 0; kt < ktiles; ++kt) {
        const int kofs = kt * 64 + cS;
#pragma unroll
        for (int i = 0; i < 4; i++) {
            const int ch = i * 4 + wv;
            const unsigned short* ga = Ab + (size_t)(bm + ch * 8 + rS) * lda + kofs;
            __builtin_amdgcn_global_load_lds((gas_ptr)ga, (lds_ptr)&Al[ch * 512], 16, 0, 0);
        }
#pragma unroll
        for (int i = 0; i < TN / 32; i++) {
            const int ch = i * 4 + wv;
            const unsigned short* gb = Bb + (size_t)(bn + ch * 8 + rS) * ldb + kofs;
            __builtin_amdgcn_global_load_lds((gas_ptr)gb, (lds_ptr)&Bl[ch * 512], 16, 0, 0);
        }
        __syncthreads();

#pragma unroll
        for (int kk = 0; kk < 2; kk++) {
            const int cg = ((kk * 4 + quad) ^ fx) * 8;
            bhalf8 af[4], bf[WN];
#pragma unroll
            for (int mi = 0; mi < 4; mi++)
                af[mi] = *(const bhalf8*)&Al[(wm + mi * 16 + l16) * 64 + cg];
#pragma unroll
            for (int ni = 0; ni < WN; ni++)
                bf[ni] = *(const bhalf8*)&Bl[(wn + ni * 16 + l16) * 64 + cg];
#pragma unroll
            for (int mi = 0; mi < 4; mi++)
#pragma unroll
                for (int ni = 0; ni < WN; ni++)
                    acc[mi][ni] = __builtin_amdgcn_mfma_f32_16x16x32_bf16(af[mi], bf[ni],
                                                                         acc[mi][ni], 0, 0, 0);
        }
        __syncthreads();
    }

#pragma unroll
    for (int mi = 0; mi < 4; mi++)
#pragma unroll
        for (int ni = 0; ni < WN; ni++)
#pragma unroll
            for (int r = 0; r < 4; r++) {
                int gm = bm + wm + mi * 16 + quad * 4 + r;
                int gn = bn + wn + ni * 16 + l16;
                float v = acc[mi][ni][r];
                size_t cidx = (size_t)sC * bz + (size_t)gm * ldc + gn;
                if constexpr (MODE == 0) {
                    v = mish_f(v + bias[gn]);
                    ((unsigned short*)Cp)[cidx] = f2bf(v);
                } else if constexpr (MODE == 1) {
                    size_t si = (size_t)bz * biasStride + gn;
                    float rr = rsqrtf(fmaxf(sumsq[si], 1e-24f));
                    v = v * rr + bias[si];
                    ((unsigned short*)Cp)[cidx] = f2bf(v);
                } else {
                    v += bias[gn] + bf2f(residbf[cidx]);
                    ((float*)Cp)[cidx] = v;
                }
            }
}

// ---------------- launch ----------------

extern "C" void kernel_launch(void* const* d_in, const int* in_sizes, int n_in,
                              void* d_out, int out_size, void* d_ws, size_t ws_size,
                              hipStream_t stream) {
    const float* input = (const float*)d_in[0];
    const float* d_w   = (const float*)d_in[1];
    const float* d_g   = (const float*)d_in[2];
    const float* d_b   = (const float*)d_in[3];
    const float* p_w   = (const float*)d_in[4];
    const float* p_g   = (const float*)d_in[5];
    const float* p_b   = (const float*)d_in[6];
    const float* w1_w  = (const float*)d_in[7];
    const float* w1_b  = (const float*)d_in[8];
    const float* w2_w  = (const float*)d_in[9];
    const float* w2_b  = (const float*)d_in[10];
    float* out = (float*)d_out;

    char* ws = (char*)d_ws;
    size_t off = 0;
    auto alloc = [&](size_t bytes) {
        char* p = ws + off;
        off += (bytes + 255) & ~(size_t)255;
        return p;
    };
    float* dwn_s         = (float*)alloc((size_t)BCNT * H1 * KW * 4);
    float* sumsq         = (float*)alloc((size_t)BCNT * H2 * 4);
    unsigned short* inbf = (unsigned short*)alloc((size_t)BCNT * TT * DIN * 2);
    unsigned short* w1bf = (unsigned short*)alloc((size_t)H1 * DIN * 2);
    unsigned short* w2bf = (unsigned short*)alloc((size_t)DIN * H2 * 2);
    unsigned short* h    = (unsigned short*)alloc((size_t)BCNT * TT * H1 * 2);
    unsigned short* y    = (unsigned short*)alloc((size_t)BCNT * TT * H1 * 2);
    unsigned short* pwTu = (unsigned short*)alloc((size_t)BCNT * H2 * H1 * 2);
    unsigned short* zt   = (unsigned short*)alloc((size_t)BCNT * TT * H2 * 2);

    // f32 -> bf16 conversions + zero sumsq (one launch)
    const int n4_in = BCNT * TT * DIN / 4, n4_w1 = H1 * DIN / 4, n4_w2 = DIN * H2 / 4;
    const int n4_z = BCNT * H2 / 4;
    k_cvt3z<<<(n4_in + n4_w1 + n4_w2 + n4_z + 255) / 256, 256, 0, stream>>>(
        input, inbf, n4_in, w1_w, w1bf, n4_w1, w2_w, w2bf, n4_w2, sumsq, n4_z);

    // weight prep
    k_norm_dwn<<<BCNT * KW, 256, 0, stream>>>(d_w, d_g, dwn_s);
    k_tpw3<<<dim3(H1 / 32, H2 / 128, BCNT), 256, 0, stream>>>(p_w, p_g, pwTu, sumsq);

    // G1: h = bf16(mish(input @ w1_w^T + w1_b)); 64 M x 4 N = 256 blocks, 1/CU
    gemm_dp<0, 0><<<256, 512, 0, stream>>>(
        inbf, w1bf, h, DIN, DIN, DIN, H1, 0, 0, 0, w1_b, 0, nullptr);

    // depthwise conv -> y (B*T, H1) bf16; 1024 blocks, 4ch/thread
    k_conv4<<<dim3(TT / 16, 1, BCNT), 256, 0, stream>>>(h, dwn_s, d_b, y);

    // G2 (batched): zt = rsqrt(sumsq)*(y.pwTu) + p_b; 4x4x16 = 256 blocks, 1/CU
    gemm_dp<1, 1><<<256, 512, 0, stream>>>(
        y, pwTu, zt, H1, H1, H1, H2, (long)TT * H1, (long)H2 * H1, (long)TT * H2,
        p_b, H2, sumsq);

    // G3: out = zt @ w2^T + w2_b + resid; 128x64 tiles -> 768 blocks (round-0)
    gemm_nt<2, 0, 64><<<dim3(BCNT * TT / 128, DIN / 64, 1), 256, 0, stream>>>(
        zt, w2bf, out, H2, H2, H2, DIN, 0, 0, 0, w2_b, 0, nullptr, inbf);
}

// Round 6
// 264.361 us; speedup vs baseline: 1.0200x; 1.0200x over previous
//
#include <hip/hip_runtime.h>

#define BCNT 16
#define TT 1024
#define DIN 384
#define H1 1024
#define H2 1024
#define KW 9

typedef __attribute__((ext_vector_type(8))) short bhalf8;   // 8 bf16 in 4 VGPRs
typedef __attribute__((ext_vector_type(4))) float f32x4;

typedef const __attribute__((address_space(1))) void* gas_ptr;
typedef __attribute__((address_space(3))) void* lds_ptr;

__device__ __forceinline__ float bf2f(unsigned short u) {
    return __uint_as_float(((unsigned int)u) << 16);
}
__device__ __forceinline__ unsigned short f2bf(float f) {
    unsigned int u = __float_as_uint(f);
    unsigned int r = (u + 0x7FFFu + ((u >> 16) & 1u)) >> 16;  // RNE
    return (unsigned short)r;
}
// mish(x) = x*tanh(log1p(e^x)) = x*(u^2+2u)/(u^2+2u+2), u=e^x (exact algebra)
__device__ __forceinline__ float mish_f(float x) {
    if (x > 20.f) return x;
    float u = __expf(x);
    float n = u * u + 2.f * u;
    return x * n / (n + 2.f);
}

// ---------------- prep kernels ----------------

// fused f32->bf16 cvt for input, w1_w, w2_w + zero sumsq (one launch)
__global__ __launch_bounds__(256) void k_cvt3z(
    const float* __restrict__ s0, unsigned short* __restrict__ d0, int n0,
    const float* __restrict__ s1, unsigned short* __restrict__ d1, int n1,
    const float* __restrict__ s2, unsigned short* __restrict__ d2, int n2,
    float* __restrict__ zb, int n3) {
    int i = blockIdx.x * 256 + threadIdx.x;
    const float* s; unsigned short* d; int j = i;
    if (i < n0) { s = s0; d = d0; }
    else if ((j = i - n0) < n1) { s = s1; d = d1; }
    else if ((j = i - n0 - n1) < n2) { s = s2; d = d2; }
    else if ((j = i - n0 - n1 - n2) < n3) {
        ((float4*)zb)[j] = make_float4(0.f, 0.f, 0.f, 0.f);
        return;
    } else return;
    float4 v = ((const float4*)s)[j];
    ushort4 o;
    o.x = f2bf(v.x); o.y = f2bf(v.y); o.z = f2bf(v.z); o.w = f2bf(v.w);
    ((ushort4*)d)[j] = o;
}

// per-(b,k): norm of d_w over c, then write dwn_s[b,c,k] = d_w/n * d_g * T
__global__ void k_norm_dwn(const float* __restrict__ d_w, const float* __restrict__ d_g,
                           float* __restrict__ dwn_s) {
    int idx = blockIdx.x;           // b*KW + k
    int b = idx / KW, k = idx % KW;
    float s = 0.f;
    for (int c = threadIdx.x; c < H1; c += 256) {
        float v = d_w[((size_t)b * H1 + c) * KW + k];
        s += v * v;
    }
    __shared__ float red[256];
    __shared__ float nsh;
    red[threadIdx.x] = s; __syncthreads();
    for (int st = 128; st > 0; st >>= 1) {
        if (threadIdx.x < st) red[threadIdx.x] += red[threadIdx.x + st];
        __syncthreads();
    }
    if (threadIdx.x == 0) nsh = fmaxf(sqrtf(red[0]), 1e-12f);
    __syncthreads();
    float n = nsh;
    for (int c = threadIdx.x; c < H1; c += 256) {
        size_t o = ((size_t)b * H1 + c) * KW + k;
        dwn_s[o] = d_w[o] / n * d_g[b * H1 + c] * (float)TT;
    }
}

// transpose+scale p_w AND per-(b,o) sumsq. Vectorized: 32c x 128o tile,
// float4 (16B/lane) reads, 2x bhalf8 (32B/thread) transposed writes.
__global__ __launch_bounds__(256) void k_tpw3(const float* __restrict__ p_w,
                                              const float* __restrict__ p_g,
                                              unsigned short* __restrict__ pwTu,
                                              float* __restrict__ sumsq) {
    __shared__ float tile[32][132];
    __shared__ float sred[8][32][4];
    __shared__ float pg[32];
    const int tid = threadIdx.x;
    const int tx = tid & 31, ty = tid >> 5;         // 32 x 8
    const int c0 = blockIdx.x * 32, o0 = blockIdx.y * 128, b = blockIdx.z;
    if (tid < 32) pg[tid] = p_g[(size_t)b * H1 + c0 + tid];
    const float4* pw4 = (const float4*)p_w;
    float s0 = 0.f, s1 = 0.f, s2 = 0.f, s3 = 0.f;
#pragma unroll
    for (int j = 0; j < 4; j++) {
        int cl = ty + j * 8;
        float4 v = pw4[(size_t)(b * H1 + c0 + cl) * (H2 / 4) + (o0 / 4) + tx];
        *(float4*)&tile[cl][tx * 4] = v;
        s0 += v.x * v.x; s1 += v.y * v.y; s2 += v.z * v.z; s3 += v.w * v.w;
    }
    sred[ty][tx][0] = s0; sred[ty][tx][1] = s1;
    sred[ty][tx][2] = s2; sred[ty][tx][3] = s3;
    __syncthreads();
    if (tid < 128) {
        int txo = tid >> 2, q = tid & 3;
        float t = 0.f;
#pragma unroll
        for (int r = 0; r < 8; r++) t += sred[r][txo][q];
        atomicAdd(&sumsq[(size_t)b * H2 + o0 + txo * 4 + q], t);
    }
    const int ol = tid >> 1, half = (tid & 1) * 16;
    unsigned short outv[16];
#pragma unroll
    for (int i = 0; i < 16; i++)
        outv[i] = f2bf(tile[half + i][ol] * pg[half + i]);
    unsigned short* dst = &pwTu[((size_t)b * H2 + o0 + ol) * H1 + c0 + half];
    *(bhalf8*)dst = *(const bhalf8*)&outv[0];
    *(bhalf8*)&dst[8] = *(const bhalf8*)&outv[8];
}

// depthwise conv along T. Vectorized: 4 channels/thread (ushort4, 8B/lane),
// t-block 16 -> grid (64,1,16) = 1024 blocks = 4 blk/CU (16 waves/CU TLP).
__global__ __launch_bounds__(256) void k_conv4(const unsigned short* __restrict__ h,
                                               const float* __restrict__ dwn_s,
                                               const float* __restrict__ d_b,
                                               unsigned short* __restrict__ y) {
    const int tid = threadIdx.x;
    const int c = tid * 4;
    const int t0 = blockIdx.x * 16;
    const int b = blockIdx.z;
    const ushort4* hb = (const ushort4*)(h + (size_t)b * TT * H1);
    ushort4* yb = (ushort4*)(y + (size_t)b * TT * H1);
    float kk[KW][4], db[4];
#pragma unroll
    for (int q = 0; q < 4; q++) {
        db[q] = d_b[b * H1 + c + q];
#pragma unroll
        for (int i = 0; i < KW; i++)
            kk[i][q] = dwn_s[((size_t)b * H1 + c + q) * KW + i];
    }
    float w[KW][4];
#pragma unroll
    for (int i = 0; i < 8; i++) {
        int t = t0 - 4 + i;
        if (t >= 0) {
            ushort4 v = hb[(size_t)t * (H1 / 4) + tid];
            w[i][0] = bf2f(v.x); w[i][1] = bf2f(v.y);
            w[i][2] = bf2f(v.z); w[i][3] = bf2f(v.w);
        } else { w[i][0] = w[i][1] = w[i][2] = w[i][3] = 0.f; }
    }
#pragma unroll
    for (int j = 0; j < 16; j++) {
        const int t = t0 + j, tl = t + 4;
        if (tl < TT) {
            ushort4 v = hb[(size_t)tl * (H1 / 4) + tid];
            w[8][0] = bf2f(v.x); w[8][1] = bf2f(v.y);
            w[8][2] = bf2f(v.z); w[8][3] = bf2f(v.w);
        } else { w[8][0] = w[8][1] = w[8][2] = w[8][3] = 0.f; }
        float a0 = db[0], a1 = db[1], a2 = db[2], a3 = db[3];
#pragma unroll
        for (int i = 0; i < KW; i++) {
            a0 += kk[i][0] * w[i][0]; a1 += kk[i][1] * w[i][1];
            a2 += kk[i][2] * w[i][2]; a3 += kk[i][3] * w[i][3];
        }
        ushort4 o;
        o.x = f2bf(a0); o.y = f2bf(a1); o.z = f2bf(a2); o.w = f2bf(a3);
        yb[(size_t)t * (H1 / 4) + tid] = o;
#pragma unroll
        for (int i = 0; i < 8; i++) {
            w[i][0] = w[i + 1][0]; w[i][1] = w[i + 1][1];
            w[i][2] = w[i + 1][2]; w[i][3] = w[i + 1][3];
        }
    }
}

// ------- gemm_lh: 256x256 tile, BK=32, ring-3 LDS, LOOK-AHEAD schedule -------
// Same geometry/layout/index math as r5's gemm_dp (HW-verified: passed, 0 bank
// conflicts). ONLY the schedule differs: ds_reads issue ONE PHASE AHEAD of the
// MFMAs that consume them (m201's actual lever; r5 read-then-wait-then-MFMA in
// the same phase serialized reads against MFMA).
// Per 32-K step kt (steady state):
//  P1: read af4-7(kt) | STAGE(kt+2): A+B 4 loads | lgkm(4) [P1frags(kt) done,
//      af4-7 in flight] | 16 MFMA acc[0-3] | vmcnt(4) [tile kt+1 landed] | B1
//  P2: read P1frags(kt+1) [slot (kt+1)%3, landed per B1] | lgkm(8) [af4-7 done,
//      look-ahead in flight] | 16 MFMA acc[4-7] | B2
// vmcnt never 0 in steady state. WAR: STAGE(kt+2) targets slot (kt-1)%3, whose
// last readers (af4-7(kt-1)) drained by step kt-1's lgkm(8) before B2(kt-1).
// RAW: look-ahead reads follow vmcnt(4)+B1 (all waves' tile-(kt+1) loads landed).
// Unroll-by-2 with named register sets (rule #20: no runtime-indexed frag sets).
// MODE 1: C=bf16(v*rsqrt(sumsq)+bias), batched. GS 1: 4x4x16 = 256 blocks.
#define LH_STEP(KT, BFC, AFC, BFN, AFN)                                        \
  {                                                                            \
    const unsigned short* Asl = &As[(KT) % 3][0];                              \
    bhalf8 afw0 = *(const bhalf8*)&Asl[aoff + 4 * 512];                        \
    bhalf8 afw1 = *(const bhalf8*)&Asl[aoff + 5 * 512];                        \
    bhalf8 afw2 = *(const bhalf8*)&Asl[aoff + 6 * 512];                        \
    bhalf8 afw3 = *(const bhalf8*)&Asl[aoff + 7 * 512];                        \
    if ((KT) + 2 < nkt) STAGE((KT) + 2);                                       \
    asm volatile("s_waitcnt lgkmcnt(4)" ::: "memory");                         \
    __builtin_amdgcn_sched_barrier(0);                                         \
    __builtin_amdgcn_s_setprio(1);                                             \
    _Pragma("unroll") for (int mi = 0; mi < 4; mi++)                           \
      _Pragma("unroll") for (int ni = 0; ni < 4; ni++)                         \
        acc[mi][ni] = __builtin_amdgcn_mfma_f32_16x16x32_bf16(                 \
            AFC[mi], BFC[ni], acc[mi][ni], 0, 0, 0);                           \
    __builtin_amdgcn_s_setprio(0);                                             \
    if ((KT) + 2 < nkt) asm volatile("s_waitcnt vmcnt(4)" ::: "memory");       \
    else                asm volatile("s_waitcnt vmcnt(0)" ::: "memory");       \
    __builtin_amdgcn_s_barrier();                                              \
    __builtin_amdgcn_sched_barrier(0);                                         \
    if ((KT) + 1 < nkt) {                                                      \
      const unsigned short* Asn = &As[((KT) + 1) % 3][0];                      \
      const unsigned short* Bsn = &Bs[((KT) + 1) % 3][0];                      \
      BFN[0] = *(const bhalf8*)&Bsn[boff];                                     \
      BFN[1] = *(const bhalf8*)&Bsn[boff + 512];                               \
      BFN[2] = *(const bhalf8*)&Bsn[boff + 1024];                              \
      BFN[3] = *(const bhalf8*)&Bsn[boff + 1536];                              \
      AFN[0] = *(const bhalf8*)&Asn[aoff];                                     \
      AFN[1] = *(const bhalf8*)&Asn[aoff + 512];                               \
      AFN[2] = *(const bhalf8*)&Asn[aoff + 1024];                              \
      AFN[3] = *(const bhalf8*)&Asn[aoff + 1536];                              \
      asm volatile("s_waitcnt lgkmcnt(8)" ::: "memory");                       \
    } else {                                                                   \
      asm volatile("s_waitcnt lgkmcnt(0)" ::: "memory");                       \
    }                                                                          \
    __builtin_amdgcn_sched_barrier(0);                                         \
    __builtin_amdgcn_s_setprio(1);                                             \
    _Pragma("unroll") for (int ni = 0; ni < 4; ni++)                           \
      acc[4][ni] = __builtin_amdgcn_mfma_f32_16x16x32_bf16(afw0, BFC[ni],      \
                                                           acc[4][ni], 0, 0, 0);\
    _Pragma("unroll") for (int ni = 0; ni < 4; ni++)                           \
      acc[5][ni] = __builtin_amdgcn_mfma_f32_16x16x32_bf16(afw1, BFC[ni],      \
                                                           acc[5][ni], 0, 0, 0);\
    _Pragma("unroll") for (int ni = 0; ni < 4; ni++)                           \
      acc[6][ni] = __builtin_amdgcn_mfma_f32_16x16x32_bf16(afw2, BFC[ni],      \
                                                           acc[6][ni], 0, 0, 0);\
    _Pragma("unroll") for (int ni = 0; ni < 4; ni++)                           \
      acc[7][ni] = __builtin_amdgcn_mfma_f32_16x16x32_bf16(afw3, BFC[ni],      \
                                                           acc[7][ni], 0, 0, 0);\
    __builtin_amdgcn_s_setprio(0);                                             \
    __builtin_amdgcn_s_barrier();                                              \
  }

template <int MODE, int GS>
__global__ __launch_bounds__(512, 2) void gemm_lh(
    const unsigned short* __restrict__ A, const unsigned short* __restrict__ Bm,
    unsigned short* __restrict__ Cp, int Kdim, int lda, int ldb, int ldc,
    long sA, long sB, long sC,
    const float* __restrict__ bias, int biasStride,
    const float* __restrict__ sumsq) {
    __shared__ __attribute__((aligned(16))) unsigned short As[3][128 * 64];
    __shared__ __attribute__((aligned(16))) unsigned short Bs[3][128 * 64];

    const int tid = threadIdx.x;
    const int lane = tid & 63, wv = tid >> 6;       // 8 waves
    const int wr = wv >> 2, wc = wv & 3;            // 2 x 4 wave grid

    int bx, by, bz;
    {
        int l = blockIdx.x;                         // 256 blocks, 1/CU
        int xcd = l & 7, s = l >> 3;                // s: 0..31
        if constexpr (GS == 0) { bz = 0; bx = xcd * 8 + (s & 7); by = s >> 3; }
        else { bz = xcd * 2 + (s >> 4); int u = s & 15; bx = u & 3; by = u >> 2; }
    }
    const int bm = bx * 256, bn = by * 256;
    const unsigned short* Ab = A + (size_t)sA * bz;
    const unsigned short* Bb = Bm + (size_t)sB * bz;

    // staging map (verified in r5): chunk = 8 LDS-rows (16 M-rows x 32 K)
    const int rSl = lane >> 3;
    const int gSl = (lane & 7) ^ (rSl & 7);
    const int mOf = 2 * rSl + (gSl >> 2);
    const int kOf = (gSl & 3) * 8;

    // frag-read offsets (verified in r5)
    const int l16 = lane & 15, quad = lane >> 4;
    const int Rb = l16 >> 1;
    const int gsw = ((l16 & 1) * 4 + quad) ^ (Rb & 7);
    const int aoff = (wr * 64 + Rb) * 64 + gsw * 8;   // + mi*512
    const int boff = (wc * 32 + Rb) * 64 + gsw * 8;   // + ni*512

    f32x4 acc[8][4];
#pragma unroll
    for (int i = 0; i < 8; i++)
#pragma unroll
        for (int j = 0; j < 4; j++)
#pragma unroll
            for (int r = 0; r < 4; r++) acc[i][j][r] = 0.f;

    // stage one tile: A+B, 4 loads/thread; per-thread issue order A,B,A,B
    auto STAGE = [&](int kt) {
        const int slot = kt % 3;
        const int kofs = kt * 32 + kOf;
#pragma unroll
        for (int i = 0; i < 2; i++) {
            const int ch = wv + i * 8;
            const unsigned short* ga = Ab + (size_t)(bm + ch * 16 + mOf) * lda + kofs;
            __builtin_amdgcn_global_load_lds((gas_ptr)ga, (lds_ptr)&As[slot][ch * 512], 16, 0, 0);
            const unsigned short* gb = Bb + (size_t)(bn + ch * 16 + mOf) * ldb + kofs;
            __builtin_amdgcn_global_load_lds((gas_ptr)gb, (lds_ptr)&Bs[slot][ch * 512], 16, 0, 0);
        }
    };

    const int nkt = Kdim / 32;                       // even for all our K
    STAGE(0); STAGE(1);                              // 8 loads in flight
    asm volatile("s_waitcnt vmcnt(4)" ::: "memory"); // tile 0 landed
    __builtin_amdgcn_s_barrier();
    __builtin_amdgcn_sched_barrier(0);

    bhalf8 bfE[4], afE[4], bfO[4], afO[4];
    {
        const unsigned short* As0 = &As[0][0];
        const unsigned short* Bs0 = &Bs[0][0];
        bfE[0] = *(const bhalf8*)&Bs0[boff];
        bfE[1] = *(const bhalf8*)&Bs0[boff + 512];
        bfE[2] = *(const bhalf8*)&Bs0[boff + 1024];
        bfE[3] = *(const bhalf8*)&Bs0[boff + 1536];
        afE[0] = *(const bhalf8*)&As0[aoff];
        afE[1] = *(const bhalf8*)&As0[aoff + 512];
        afE[2] = *(const bhalf8*)&As0[aoff + 1024];
        afE[3] = *(const bhalf8*)&As0[aoff + 1536];
    }

    for (int kt = 0; kt < nkt; kt += 2) {
        LH_STEP(kt, bfE, afE, bfO, afO);
        LH_STEP(kt + 1, bfO, afO, bfE, afE);
    }

    // epilogue: frag D row = quad*4+r, col = l16
#pragma unroll
    for (int mi = 0; mi < 8; mi++)
#pragma unroll
        for (int ni = 0; ni < 4; ni++)
#pragma unroll
            for (int r = 0; r < 4; r++) {
                int gm = bm + wr * 128 + mi * 16 + quad * 4 + r;
                int gn = bn + wc * 64 + ni * 16 + l16;
                float v = acc[mi][ni][r];
                size_t cidx = (size_t)sC * bz + (size_t)gm * ldc + gn;
                if constexpr (MODE == 0) {
                    v = mish_f(v + bias[gn]);
                    Cp[cidx] = f2bf(v);
                } else {
                    size_t si = (size_t)bz * biasStride + gn;
                    float rr = rsqrtf(fmaxf(sumsq[si], 1e-24f));
                    v = v * rr + bias[si];
                    Cp[cidx] = f2bf(v);
                }
            }
}

// ------- bf16 NT MFMA GEMM (round-0 structure, best measured): 128 x TN tile -------
// C[m,n] = sum_k A[m,k]*B[n,k], bf16 K-contiguous. BK=64. 4 blocks/CU.
// MODE 0: C=bf16(mish(v + bias[n]))
// MODE 1: C=bf16(v*rsqrt(sumsq[bz*str+n]) + bias[bz*str+n])
// MODE 2: C=f32 (v + bias[n] + bf2f(residbf[idx]))
template <int MODE, int SWIZ, int TN>
__global__ __launch_bounds__(256, 4) void gemm_nt(
    const unsigned short* __restrict__ A, const unsigned short* __restrict__ Bm,
    void* __restrict__ Cp, int Kdim, int lda, int ldb, int ldc,
    long sA, long sB, long sC,
    const float* __restrict__ bias, int biasStride,
    const float* __restrict__ sumsq,
    const unsigned short* __restrict__ residbf) {
    constexpr int WN = TN / 32;
    __shared__ __attribute__((aligned(16))) unsigned short Al[128 * 64];
    __shared__ __attribute__((aligned(16))) unsigned short Bl[TN * 64];

    const int tid = threadIdx.x;
    const int lane = tid & 63, wv = tid >> 6;

    int bx, by, bz;
    if constexpr (SWIZ) {
        int l = blockIdx.x;
        int xcd = l & 7, s = l >> 3;
        bz = xcd * 2 + (s >> 6);
        int u = s & 63;
        bx = u & 7; by = u >> 3;
    } else {
        bx = blockIdx.x; by = blockIdx.y; bz = blockIdx.z;
    }
    const int bm = bx * 128, bn = by * TN;

    const unsigned short* Ab = A + (size_t)sA * bz;
    const unsigned short* Bb = Bm + (size_t)sB * bz;

    const int rS = lane >> 3;
    const int cS = ((lane & 7) ^ (rS & 7)) * 8;

    const int wm = (wv >> 1) * 64, wn = (wv & 1) * (TN / 2);
    const int l16 = lane & 15, quad = lane >> 4;
    const int fx = l16 & 7;

    f32x4 acc[4][WN];
#pragma unroll
    for (int i = 0; i < 4; i++)
#pragma unroll
        for (int j = 0; j < WN; j++)
#pragma unroll
            for (int r = 0; r < 4; r++) acc[i][j][r] = 0.f;

    const int ktiles = Kdim / 64;
    for (int kt = 0; kt < ktiles; ++kt) {
        const int kofs = kt * 64 + cS;
#pragma unroll
        for (int i = 0; i < 4; i++) {
            const int ch = i * 4 + wv;
            const unsigned short* ga = Ab + (size_t)(bm + ch * 8 + rS) * lda + kofs;
            __builtin_amdgcn_global_load_lds((gas_ptr)ga, (lds_ptr)&Al[ch * 512], 16, 0, 0);
        }
#pragma unroll
        for (int i = 0; i < TN / 32; i++) {
            const int ch = i * 4 + wv;
            const unsigned short* gb = Bb + (size_t)(bn + ch * 8 + rS) * ldb + kofs;
            __builtin_amdgcn_global_load_lds((gas_ptr)gb, (lds_ptr)&Bl[ch * 512], 16, 0, 0);
        }
        __syncthreads();

#pragma unroll
        for (int kk = 0; kk < 2; kk++) {
            const int cg = ((kk * 4 + quad) ^ fx) * 8;
            bhalf8 af[4], bf[WN];
#pragma unroll
            for (int mi = 0; mi < 4; mi++)
                af[mi] = *(const bhalf8*)&Al[(wm + mi * 16 + l16) * 64 + cg];
#pragma unroll
            for (int ni = 0; ni < WN; ni++)
                bf[ni] = *(const bhalf8*)&Bl[(wn + ni * 16 + l16) * 64 + cg];
#pragma unroll
            for (int mi = 0; mi < 4; mi++)
#pragma unroll
                for (int ni = 0; ni < WN; ni++)
                    acc[mi][ni] = __builtin_amdgcn_mfma_f32_16x16x32_bf16(af[mi], bf[ni],
                                                                         acc[mi][ni], 0, 0, 0);
        }
        __syncthreads();
    }

#pragma unroll
    for (int mi = 0; mi < 4; mi++)
#pragma unroll
        for (int ni = 0; ni < WN; ni++)
#pragma unroll
            for (int r = 0; r < 4; r++) {
                int gm = bm + wm + mi * 16 + quad * 4 + r;
                int gn = bn + wn + ni * 16 + l16;
                float v = acc[mi][ni][r];
                size_t cidx = (size_t)sC * bz + (size_t)gm * ldc + gn;
                if constexpr (MODE == 0) {
                    v = mish_f(v + bias[gn]);
                    ((unsigned short*)Cp)[cidx] = f2bf(v);
                } else if constexpr (MODE == 1) {
                    size_t si = (size_t)bz * biasStride + gn;
                    float rr = rsqrtf(fmaxf(sumsq[si], 1e-24f));
                    v = v * rr + bias[si];
                    ((unsigned short*)Cp)[cidx] = f2bf(v);
                } else {
                    v += bias[gn] + bf2f(residbf[cidx]);
                    ((float*)Cp)[cidx] = v;
                }
            }
}

// ---------------- launch ----------------

extern "C" void kernel_launch(void* const* d_in, const int* in_sizes, int n_in,
                              void* d_out, int out_size, void* d_ws, size_t ws_size,
                              hipStream_t stream) {
    const float* input = (const float*)d_in[0];
    const float* d_w   = (const float*)d_in[1];
    const float* d_g   = (const float*)d_in[2];
    const float* d_b   = (const float*)d_in[3];
    const float* p_w   = (const float*)d_in[4];
    const float* p_g   = (const float*)d_in[5];
    const float* p_b   = (const float*)d_in[6];
    const float* w1_w  = (const float*)d_in[7];
    const float* w1_b  = (const float*)d_in[8];
    const float* w2_w  = (const float*)d_in[9];
    const float* w2_b  = (const float*)d_in[10];
    float* out = (float*)d_out;

    char* ws = (char*)d_ws;
    size_t off = 0;
    auto alloc = [&](size_t bytes) {
        char* p = ws + off;
        off += (bytes + 255) & ~(size_t)255;
        return p;
    };
    float* dwn_s         = (float*)alloc((size_t)BCNT * H1 * KW * 4);
    float* sumsq         = (float*)alloc((size_t)BCNT * H2 * 4);
    unsigned short* inbf = (unsigned short*)alloc((size_t)BCNT * TT * DIN * 2);
    unsigned short* w1bf = (unsigned short*)alloc((size_t)H1 * DIN * 2);
    unsigned short* w2bf = (unsigned short*)alloc((size_t)DIN * H2 * 2);
    unsigned short* h    = (unsigned short*)alloc((size_t)BCNT * TT * H1 * 2);
    unsigned short* y    = (unsigned short*)alloc((size_t)BCNT * TT * H1 * 2);
    unsigned short* pwTu = (unsigned short*)alloc((size_t)BCNT * H2 * H1 * 2);
    unsigned short* zt   = (unsigned short*)alloc((size_t)BCNT * TT * H2 * 2);

    // f32 -> bf16 conversions + zero sumsq (one launch)
    const int n4_in = BCNT * TT * DIN / 4, n4_w1 = H1 * DIN / 4, n4_w2 = DIN * H2 / 4;
    const int n4_z = BCNT * H2 / 4;
    k_cvt3z<<<(n4_in + n4_w1 + n4_w2 + n4_z + 255) / 256, 256, 0, stream>>>(
        input, inbf, n4_in, w1_w, w1bf, n4_w1, w2_w, w2bf, n4_w2, sumsq, n4_z);

    // weight prep
    k_norm_dwn<<<BCNT * KW, 256, 0, stream>>>(d_w, d_g, dwn_s);
    k_tpw3<<<dim3(H1 / 32, H2 / 128, BCNT), 256, 0, stream>>>(p_w, p_g, pwTu, sumsq);

    // G1: h = bf16(mish(input @ w1_w^T + w1_b)); round-4 config (control)
    gemm_nt<0, 0, 128><<<dim3(BCNT * TT / 128, H1 / 128, 1), 256, 0, stream>>>(
        inbf, w1bf, h, DIN, DIN, DIN, H1, 0, 0, 0, w1_b, 0, nullptr, nullptr);

    // depthwise conv -> y (B*T, H1) bf16; 1024 blocks, 4ch/thread
    k_conv4<<<dim3(TT / 16, 1, BCNT), 256, 0, stream>>>(h, dwn_s, d_b, y);

    // G2 (batched): zt = rsqrt(sumsq)*(y.pwTu) + p_b — look-ahead experiment
    gemm_lh<1, 1><<<256, 512, 0, stream>>>(
        y, pwTu, zt, H1, H1, H1, H2, (long)TT * H1, (long)H2 * H1, (long)TT * H2,
        p_b, H2, sumsq);

    // G3: out = zt @ w2^T + w2_b + resid; 128x64 tiles -> 768 blocks (round-0)
    gemm_nt<2, 0, 64><<<dim3(BCNT * TT / 128, DIN / 64, 1), 256, 0, stream>>>(
        zt, w2bf, out, H2, H2, H2, DIN, 0, 0, 0, w2_b, 0, nullptr, inbf);
}